// Round 2
// baseline (169.939 us; speedup 1.0000x reference)
//
#include <hip/hip_runtime.h>
#include <stdint.h>

#define BATCH 32768
#define DIM   512
#define KCLS  512

typedef __bf16    bf16x8 __attribute__((ext_vector_type(8)));
typedef float     f32x4  __attribute__((ext_vector_type(4)));
typedef float     f32x8  __attribute__((ext_vector_type(8)));
typedef uint16_t  u16x8  __attribute__((ext_vector_type(8)));

__device__ __forceinline__ uint16_t f2bf(float f) {
    // RTNE fp32 -> bf16
    uint32_t u = __float_as_uint(f);
    u += 0x7FFFu + ((u >> 16) & 1u);
    return (uint16_t)(u >> 16);
}

union bfcast { u16x8 u; bf16x8 b; };

// ---------------------------------------------------------------------------
// Prep: means (K x D fp32) -> bf16 pre-swizzled into MFMA B-fragment order.
// B-frag for mfma_f32_16x16x32_bf16: B[k = 8*(lane>>4)+j][n = lane&15].
// Bsw layout: index = (((c16*16 + ch)*64) + lane)*8, col = 16*c16 + (lane&15),
// k = 32*ch + 8*(lane>>4) + j.  Also computes inv_var/alpha/beta per class.
// 128 blocks x 256 threads; each wave handles one class.
// ---------------------------------------------------------------------------
__global__ __launch_bounds__(256) void gmm_prep(
    const float* __restrict__ means,
    const float* __restrict__ log_vars,
    const float* __restrict__ log_weights,
    uint16_t* __restrict__ Bsw,
    float* __restrict__ invv_a,
    float* __restrict__ alpha_a,
    float* __restrict__ beta_a)
{
    const int k = blockIdx.x * 4 + (threadIdx.x >> 6);  // class index
    const int l = threadIdx.x & 63;                     // lane: elems 8l..8l+7

    const float* mrow = means + (size_t)k * DIM + l * 8;
    f32x4 v0 = *(const f32x4*)(mrow);
    f32x4 v1 = *(const f32x4*)(mrow + 4);

    u16x8 pk;
    pk[0] = f2bf(v0[0]); pk[1] = f2bf(v0[1]); pk[2] = f2bf(v0[2]); pk[3] = f2bf(v0[3]);
    pk[4] = f2bf(v1[0]); pk[5] = f2bf(v1[1]); pk[6] = f2bf(v1[2]); pk[7] = f2bf(v1[3]);

    // writer slot: this lane's 8 elements are k-offsets 8l..8l+7 = 32*ch + 8*hh
    const int c16 = k >> 4, r = k & 15, ch = l >> 2, hh = l & 3;
    *(u16x8*)(Bsw + ((((c16 * 16) + ch) * 64) + (hh * 16 + r)) * 8) = pk;

    float sq = v0[0]*v0[0] + v0[1]*v0[1] + v0[2]*v0[2] + v0[3]*v0[3]
             + v1[0]*v1[0] + v1[1]*v1[1] + v1[2]*v1[2] + v1[3]*v1[3];
    #pragma unroll
    for (int m = 1; m <= 32; m <<= 1) sq += __shfl_xor(sq, m);

    if (l == 0) {
        const float lv = log_vars[k];
        const float iv = __expf(-lv);
        invv_a[k]  = iv;
        alpha_a[k] = -0.5f * iv;
        // log_softmax(log_weights) minus its row-constant LSE (cancels in softmax)
        beta_a[k]  = -0.5f * (sq * iv + (float)DIM * lv) + log_weights[k];
    }
}

// ---------------------------------------------------------------------------
// Main fused kernel: 32 rows/block, full K=512 in-block -> fused softmax.
// BARRIER-FREE K-loop: A-fragments loaded straight from global (32 B / lane
// contiguous, RTNE-converted in-register), B-fragments from L2-resident
// pre-swizzled Bsw (16 B / lane). All 4 waves read the same 32-row x-tile
// (L1/L2 hits after the first toucher); no LDS in the hot loop at all.
// ---------------------------------------------------------------------------
__global__ __launch_bounds__(256, 3) void gmm_main(
    const float* __restrict__ x,
    const uint16_t* __restrict__ Bsw,
    const float* __restrict__ invv_a,
    const float* __restrict__ alpha_a,
    const float* __restrict__ beta_a,
    float* __restrict__ out)
{
    __shared__ float pmax[4][32];
    __shared__ float psum[4][32];

    const int t    = threadIdx.x;
    const int w    = t >> 6;        // wave 0..3 -> col group
    const int lane = t & 63;
    const int r16  = lane & 15;     // fragment row (A) / col (B/C)
    const int h    = lane >> 4;     // k-group / C row-quad
    const int row0 = blockIdx.x * 32;

    f32x4 acc[2][8];
    #pragma unroll
    for (int rt = 0; rt < 2; ++rt)
        #pragma unroll
        for (int ct = 0; ct < 8; ++ct)
            acc[rt][ct] = (f32x4){0.f, 0.f, 0.f, 0.f};

    // A source: lane (r16,h) reads x[row0 + 16*rt + r16][32*chk + 8*h .. +7]
    const float* xA = x + (size_t)(row0 + r16) * DIM + 8 * h;
    const uint16_t* bbase = Bsw + (size_t)w * 65536 + (size_t)lane * 8;

    float xsq0 = 0.f, xsq1 = 0.f;

    for (int chk = 0; chk < 16; ++chk) {
        const float* pa = xA + 32 * chk;
        f32x8 a0 = *(const f32x8*)(pa);
        f32x8 a1 = *(const f32x8*)(pa + 16 * DIM);

        bfcast c0, c1;
        #pragma unroll
        for (int j = 0; j < 8; ++j) {
            xsq0 += a0[j] * a0[j];
            xsq1 += a1[j] * a1[j];
            c0.u[j] = f2bf(a0[j]);
            c1.u[j] = f2bf(a1[j]);
        }

        bf16x8 bfrag[8];
        #pragma unroll
        for (int ct = 0; ct < 8; ++ct)
            bfrag[ct] = *(const bf16x8*)(bbase + ct * 8192 + chk * 512);

        #pragma unroll
        for (int ct = 0; ct < 8; ++ct) {
            acc[0][ct] = __builtin_amdgcn_mfma_f32_16x16x32_bf16(c0.b, bfrag[ct], acc[0][ct], 0, 0, 0);
            acc[1][ct] = __builtin_amdgcn_mfma_f32_16x16x32_bf16(c1.b, bfrag[ct], acc[1][ct], 0, 0, 0);
        }
    }

    // ---- x_sq: lane (r16,h) holds partial of rows r16 / 16+r16; reduce over h ----
    xsq0 += __shfl_xor(xsq0, 16); xsq0 += __shfl_xor(xsq0, 32);
    xsq1 += __shfl_xor(xsq1, 16); xsq1 += __shfl_xor(xsq1, 32);
    // lane needs xsq of C-rows rl = 16*rt + 4*h + reg  -> source lane 4*h+reg
    float xsq[2][4];
    #pragma unroll
    for (int reg = 0; reg < 4; ++reg) {
        xsq[0][reg] = __shfl(xsq0, 4 * h + reg);
        xsq[1][reg] = __shfl(xsq1, 4 * h + reg);
    }

    // ---- per-column affine params (L2-hot) ----
    float invv[8], alf[8], bet[8];
    #pragma unroll
    for (int ct = 0; ct < 8; ++ct) {
        const int col = 128 * w + 16 * ct + r16;
        invv[ct] = invv_a[col];
        alf[ct]  = alpha_a[col];
        bet[ct]  = beta_a[col];
    }

    // ---- logits + per-row max (C layout: col=lane&15, row=4*(lane>>4)+reg) ----
    float mr[2][4];
    #pragma unroll
    for (int rt = 0; rt < 2; ++rt) {
        #pragma unroll
        for (int reg = 0; reg < 4; ++reg) {
            float m = -1e30f;
            #pragma unroll
            for (int ct = 0; ct < 8; ++ct) {
                const float v = acc[rt][ct][reg] * invv[ct] + (alf[ct] * xsq[rt][reg] + bet[ct]);
                acc[rt][ct][reg] = v;
                m = fmaxf(m, v);
            }
            m = fmaxf(m, __shfl_xor(m, 1));
            m = fmaxf(m, __shfl_xor(m, 2));
            m = fmaxf(m, __shfl_xor(m, 4));
            m = fmaxf(m, __shfl_xor(m, 8));
            mr[rt][reg] = m;
        }
    }
    if (r16 == 0) {
        #pragma unroll
        for (int rt = 0; rt < 2; ++rt)
            #pragma unroll
            for (int reg = 0; reg < 4; ++reg)
                pmax[w][16 * rt + 4 * h + reg] = mr[rt][reg];
    }
    __syncthreads();

    // ---- exp + per-row sum ----
    float sr[2][4];
    #pragma unroll
    for (int rt = 0; rt < 2; ++rt) {
        #pragma unroll
        for (int reg = 0; reg < 4; ++reg) {
            const int rl = 16 * rt + 4 * h + reg;
            const float m = fmaxf(fmaxf(pmax[0][rl], pmax[1][rl]),
                                  fmaxf(pmax[2][rl], pmax[3][rl]));
            float s = 0.f;
            #pragma unroll
            for (int ct = 0; ct < 8; ++ct) {
                const float e = __expf(acc[rt][ct][reg] - m);
                acc[rt][ct][reg] = e;
                s += e;
            }
            s += __shfl_xor(s, 1);
            s += __shfl_xor(s, 2);
            s += __shfl_xor(s, 4);
            s += __shfl_xor(s, 8);
            sr[rt][reg] = s;
        }
    }
    if (r16 == 0) {
        #pragma unroll
        for (int rt = 0; rt < 2; ++rt)
            #pragma unroll
            for (int reg = 0; reg < 4; ++reg)
                psum[w][16 * rt + 4 * h + reg] = sr[rt][reg];
    }
    __syncthreads();

    // ---- normalize + store ----
    #pragma unroll
    for (int rt = 0; rt < 2; ++rt) {
        #pragma unroll
        for (int reg = 0; reg < 4; ++reg) {
            const int rl = 16 * rt + 4 * h + reg;
            const float tot = (psum[0][rl] + psum[1][rl]) + (psum[2][rl] + psum[3][rl]);
            const float rinv = 1.0f / tot;
            float* orow = out + (size_t)(row0 + rl) * KCLS + 128 * w + r16;
            #pragma unroll
            for (int ct = 0; ct < 8; ++ct)
                orow[16 * ct] = acc[rt][ct][reg] * rinv;
        }
    }
}

extern "C" void kernel_launch(void* const* d_in, const int* in_sizes, int n_in,
                              void* d_out, int out_size, void* d_ws, size_t ws_size,
                              hipStream_t stream) {
    (void)in_sizes; (void)n_in; (void)out_size; (void)ws_size;
    const float* x           = (const float*)d_in[0];
    const float* means       = (const float*)d_in[1];
    const float* log_vars    = (const float*)d_in[2];
    const float* log_weights = (const float*)d_in[3];
    float* out = (float*)d_out;

    // ws: [0, 512KB) swizzled bf16 means; then inv_var/alpha/beta (512 f32 each)
    uint16_t* Bsw = (uint16_t*)d_ws;
    float* invv_a  = (float*)((char*)d_ws + (512u << 10));
    float* alpha_a = invv_a + KCLS;
    float* beta_a  = alpha_a + KCLS;

    gmm_prep<<<KCLS / 4, 256, 0, stream>>>(means, log_vars, log_weights,
                                           Bsw, invv_a, alpha_a, beta_a);
    gmm_main<<<BATCH / 32, 256, 0, stream>>>(x, Bsw, invv_a, alpha_a, beta_a, out);
}

// Round 3
// 163.540 us; speedup vs baseline: 1.0391x; 1.0391x over previous
//
#include <hip/hip_runtime.h>
#include <stdint.h>

#define BATCH 32768
#define DIM   512
#define KCLS  512

typedef __bf16    bf16x8 __attribute__((ext_vector_type(8)));
typedef float     f32x4  __attribute__((ext_vector_type(4)));
typedef float     f32x8  __attribute__((ext_vector_type(8)));
typedef uint16_t  u16x8  __attribute__((ext_vector_type(8)));

__device__ __forceinline__ uint16_t f2bf(float f) {
    // RTNE fp32 -> bf16
    uint32_t u = __float_as_uint(f);
    u += 0x7FFFu + ((u >> 16) & 1u);
    return (uint16_t)(u >> 16);
}

#define MFMA(a, b, c) __builtin_amdgcn_mfma_f32_16x16x32_bf16((a), (b), (c), 0, 0, 0)

// ---------------------------------------------------------------------------
// Prep: means (K x D fp32) -> bf16 pre-swizzled into MFMA B-fragment order.
// B-frag for mfma_f32_16x16x32_bf16: B[k = 8*(lane>>4)+j][n = lane&15].
// Bsw layout: index = (((c16*16 + ch)*64) + lane)*8, col = 16*c16 + (lane&15),
// k = 32*ch + 8*(lane>>4) + j.  Also computes inv_var/alpha/beta per class.
// ---------------------------------------------------------------------------
__global__ __launch_bounds__(256) void gmm_prep(
    const float* __restrict__ means,
    const float* __restrict__ log_vars,
    const float* __restrict__ log_weights,
    uint16_t* __restrict__ Bsw,
    float* __restrict__ invv_a,
    float* __restrict__ alpha_a,
    float* __restrict__ beta_a)
{
    const int k = blockIdx.x * 4 + (threadIdx.x >> 6);  // class index
    const int l = threadIdx.x & 63;                     // lane: elems 8l..8l+7

    const float* mrow = means + (size_t)k * DIM + l * 8;
    f32x4 v0 = *(const f32x4*)(mrow);
    f32x4 v1 = *(const f32x4*)(mrow + 4);

    u16x8 pk;
    pk[0] = f2bf(v0[0]); pk[1] = f2bf(v0[1]); pk[2] = f2bf(v0[2]); pk[3] = f2bf(v0[3]);
    pk[4] = f2bf(v1[0]); pk[5] = f2bf(v1[1]); pk[6] = f2bf(v1[2]); pk[7] = f2bf(v1[3]);

    const int c16 = k >> 4, r = k & 15, ch = l >> 2, hh = l & 3;
    *(u16x8*)(Bsw + ((((c16 * 16) + ch) * 64) + (hh * 16 + r)) * 8) = pk;

    float sq = v0[0]*v0[0] + v0[1]*v0[1] + v0[2]*v0[2] + v0[3]*v0[3]
             + v1[0]*v1[0] + v1[1]*v1[1] + v1[2]*v1[2] + v1[3]*v1[3];
    #pragma unroll
    for (int m = 1; m <= 32; m <<= 1) sq += __shfl_xor(sq, m);

    if (l == 0) {
        const float lv = log_vars[k];
        const float iv = __expf(-lv);
        invv_a[k]  = iv;
        alpha_a[k] = -0.5f * iv;
        beta_a[k]  = -0.5f * (sq * iv + (float)DIM * lv) + log_weights[k];
    }
}

// ---------------------------------------------------------------------------
// Main fused kernel: 32 rows/block, full K=512 in-block -> fused softmax.
// Stage x-tile to LDS ONCE (bf16, A-fragment order: idx=((chk*2+rt)*64+lane)*8
// -> lane-linear 16B, conflict-free ds_read_b128), one barrier, then a
// BARRIER-FREE software-pipelined K-loop: chunk k+1's A(ds)/B(L2) loads are
// issued while chunk k's MFMAs run (explicit 2-stage register double-buffer).
// ---------------------------------------------------------------------------
__global__ __launch_bounds__(256, 3) void gmm_main(
    const float* __restrict__ x,
    const uint16_t* __restrict__ Bsw,
    const float* __restrict__ invv_a,
    const float* __restrict__ alpha_a,
    const float* __restrict__ beta_a,
    float* __restrict__ out)
{
    __shared__ uint16_t As[16384];   // 32 KB
    __shared__ float xsq_lds[32];
    __shared__ float pmax[4][32];
    __shared__ float psum[4][32];

    const int t    = threadIdx.x;
    const int w    = t >> 6;        // wave -> col group
    const int lane = t & 63;
    const int r16  = lane & 15;
    const int h    = lane >> 4;
    const int row0 = blockIdx.x * 32;

    // ---- stage x tile -> LDS (fragment order) + xsq ----
    {
        const int srow = t >> 3, sp = t & 7;         // 8 threads per row
        const int rt_s = srow >> 4, r16_s = srow & 15;
        const float* xr = x + (size_t)(row0 + srow) * DIM;
        float xsq_p = 0.f;
        #pragma unroll
        for (int i = 0; i < 8; ++i) {
            const int o = sp + 8 * i;                // k-octet 0..63
            f32x8 v = *(const f32x8*)(xr + 8 * o);
            u16x8 pk;
            #pragma unroll
            for (int j = 0; j < 8; ++j) { xsq_p += v[j] * v[j]; pk[j] = f2bf(v[j]); }
            const int c = o >> 2, hh = o & 3;
            *(u16x8*)&As[(((c * 2 + rt_s) * 64) + hh * 16 + r16_s) * 8] = pk;
        }
        xsq_p += __shfl_xor(xsq_p, 1);
        xsq_p += __shfl_xor(xsq_p, 2);
        xsq_p += __shfl_xor(xsq_p, 4);
        if (sp == 0) xsq_lds[srow] = xsq_p;
    }
    __syncthreads();

    f32x4 acc[2][8];
    #pragma unroll
    for (int rt = 0; rt < 2; ++rt)
        #pragma unroll
        for (int ct = 0; ct < 8; ++ct)
            acc[rt][ct] = (f32x4){0.f, 0.f, 0.f, 0.f};

    const uint16_t* bb = Bsw + (size_t)w * 65536 + (size_t)lane * 8;
    const uint16_t* ab = As + (size_t)lane * 8;     // LDS, frag base

    // ---- software-pipelined K-loop (16 chunks, 2 per unrolled iter) ----
    bf16x8 Aa0, Aa1, Ab0, Ab1, Ba[8], Bb[8];
    Aa0 = *(const bf16x8*)(ab);
    Aa1 = *(const bf16x8*)(ab + 512);
    #pragma unroll
    for (int ct = 0; ct < 8; ++ct) Ba[ct] = *(const bf16x8*)(bb + ct * 8192);

    #pragma unroll
    for (int c2 = 0; c2 < 8; ++c2) {
        const int k1 = 2 * c2 + 1, k2 = 2 * c2 + 2;

        // prefetch chunk k1 into 'b' set
        Ab0 = *(const bf16x8*)(ab + k1 * 1024);
        Ab1 = *(const bf16x8*)(ab + k1 * 1024 + 512);
        #pragma unroll
        for (int ct = 0; ct < 8; ++ct)
            Bb[ct] = *(const bf16x8*)(bb + ct * 8192 + k1 * 512);

        #pragma unroll
        for (int ct = 0; ct < 8; ++ct) {
            acc[0][ct] = MFMA(Aa0, Ba[ct], acc[0][ct]);
            acc[1][ct] = MFMA(Aa1, Ba[ct], acc[1][ct]);
        }

        if (c2 < 7) {   // prefetch chunk k2 into 'a' set
            Aa0 = *(const bf16x8*)(ab + k2 * 1024);
            Aa1 = *(const bf16x8*)(ab + k2 * 1024 + 512);
            #pragma unroll
            for (int ct = 0; ct < 8; ++ct)
                Ba[ct] = *(const bf16x8*)(bb + ct * 8192 + k2 * 512);
        }

        #pragma unroll
        for (int ct = 0; ct < 8; ++ct) {
            acc[0][ct] = MFMA(Ab0, Bb[ct], acc[0][ct]);
            acc[1][ct] = MFMA(Ab1, Bb[ct], acc[1][ct]);
        }
    }

    // ---- per-column affine params (L2-hot) ----
    float invv[8], alf[8], bet[8];
    #pragma unroll
    for (int ct = 0; ct < 8; ++ct) {
        const int col = 128 * w + 16 * ct + r16;
        invv[ct] = invv_a[col];
        alf[ct]  = alpha_a[col];
        bet[ct]  = beta_a[col];
    }
    float xsq[2][4];
    #pragma unroll
    for (int rt = 0; rt < 2; ++rt)
        #pragma unroll
        for (int reg = 0; reg < 4; ++reg)
            xsq[rt][reg] = xsq_lds[16 * rt + 4 * h + reg];

    // ---- logits + per-row max (C layout: col=lane&15, row=4*(lane>>4)+reg) ----
    float mr[2][4];
    #pragma unroll
    for (int rt = 0; rt < 2; ++rt) {
        #pragma unroll
        for (int reg = 0; reg < 4; ++reg) {
            float m = -1e30f;
            #pragma unroll
            for (int ct = 0; ct < 8; ++ct) {
                const float v = acc[rt][ct][reg] * invv[ct] + (alf[ct] * xsq[rt][reg] + bet[ct]);
                acc[rt][ct][reg] = v;
                m = fmaxf(m, v);
            }
            m = fmaxf(m, __shfl_xor(m, 1));
            m = fmaxf(m, __shfl_xor(m, 2));
            m = fmaxf(m, __shfl_xor(m, 4));
            m = fmaxf(m, __shfl_xor(m, 8));
            mr[rt][reg] = m;
        }
    }
    if (r16 == 0) {
        #pragma unroll
        for (int rt = 0; rt < 2; ++rt)
            #pragma unroll
            for (int reg = 0; reg < 4; ++reg)
                pmax[w][16 * rt + 4 * h + reg] = mr[rt][reg];
    }
    __syncthreads();

    // ---- exp + per-row sum ----
    float sr[2][4];
    #pragma unroll
    for (int rt = 0; rt < 2; ++rt) {
        #pragma unroll
        for (int reg = 0; reg < 4; ++reg) {
            const int rl = 16 * rt + 4 * h + reg;
            const float m = fmaxf(fmaxf(pmax[0][rl], pmax[1][rl]),
                                  fmaxf(pmax[2][rl], pmax[3][rl]));
            float s = 0.f;
            #pragma unroll
            for (int ct = 0; ct < 8; ++ct) {
                const float e = __expf(acc[rt][ct][reg] - m);
                acc[rt][ct][reg] = e;
                s += e;
            }
            s += __shfl_xor(s, 1);
            s += __shfl_xor(s, 2);
            s += __shfl_xor(s, 4);
            s += __shfl_xor(s, 8);
            sr[rt][reg] = s;
        }
    }
    if (r16 == 0) {
        #pragma unroll
        for (int rt = 0; rt < 2; ++rt)
            #pragma unroll
            for (int reg = 0; reg < 4; ++reg)
                psum[w][16 * rt + 4 * h + reg] = sr[rt][reg];
    }
    __syncthreads();

    // ---- normalize + store ----
    #pragma unroll
    for (int rt = 0; rt < 2; ++rt) {
        #pragma unroll
        for (int reg = 0; reg < 4; ++reg) {
            const int rl = 16 * rt + 4 * h + reg;
            const float tot = (psum[0][rl] + psum[1][rl]) + (psum[2][rl] + psum[3][rl]);
            const float rinv = 1.0f / tot;
            float* orow = out + (size_t)(row0 + rl) * KCLS + 128 * w + r16;
            #pragma unroll
            for (int ct = 0; ct < 8; ++ct)
                orow[16 * ct] = acc[rt][ct][reg] * rinv;
        }
    }
}

extern "C" void kernel_launch(void* const* d_in, const int* in_sizes, int n_in,
                              void* d_out, int out_size, void* d_ws, size_t ws_size,
                              hipStream_t stream) {
    (void)in_sizes; (void)n_in; (void)out_size; (void)ws_size;
    const float* x           = (const float*)d_in[0];
    const float* means       = (const float*)d_in[1];
    const float* log_vars    = (const float*)d_in[2];
    const float* log_weights = (const float*)d_in[3];
    float* out = (float*)d_out;

    // ws: [0, 512KB) swizzled bf16 means; then inv_var/alpha/beta (512 f32 each)
    uint16_t* Bsw = (uint16_t*)d_ws;
    float* invv_a  = (float*)((char*)d_ws + (512u << 10));
    float* alpha_a = invv_a + KCLS;
    float* beta_a  = alpha_a + KCLS;

    gmm_prep<<<KCLS / 4, 256, 0, stream>>>(means, log_vars, log_weights,
                                           Bsw, invv_a, alpha_a, beta_a);
    gmm_main<<<BATCH / 32, 256, 0, stream>>>(x, Bsw, invv_a, alpha_a, beta_a, out);
}

// Round 4
// 135.000 us; speedup vs baseline: 1.2588x; 1.2114x over previous
//
#include <hip/hip_runtime.h>
#include <stdint.h>

#define BATCH 32768
#define DIM   512
#define KCLS  512

typedef __bf16    bf16x8 __attribute__((ext_vector_type(8)));
typedef float     f32x4  __attribute__((ext_vector_type(4)));
typedef float     f32x8  __attribute__((ext_vector_type(8)));
typedef uint16_t  u16x8  __attribute__((ext_vector_type(8)));

__device__ __forceinline__ uint16_t f2bf(float f) {
    // RTNE fp32 -> bf16
    uint32_t u = __float_as_uint(f);
    u += 0x7FFFu + ((u >> 16) & 1u);
    return (uint16_t)(u >> 16);
}

#define MFMA(a, b, c) __builtin_amdgcn_mfma_f32_16x16x32_bf16((a), (b), (c), 0, 0, 0)

// ---------------------------------------------------------------------------
// Prep: means (K x D fp32) -> bf16 pre-swizzled into MFMA B-fragment order.
// B-frag for mfma_f32_16x16x32_bf16: B[k = 8*(lane>>4)+j][n = lane&15].
// Bsw layout: index = (((c16*16 + ch)*64) + lane)*8, col = 16*c16 + (lane&15),
// k = 32*ch + 8*(lane>>4) + j.  Also computes inv_var/alpha/beta per class.
// ---------------------------------------------------------------------------
__global__ __launch_bounds__(256) void gmm_prep(
    const float* __restrict__ means,
    const float* __restrict__ log_vars,
    const float* __restrict__ log_weights,
    uint16_t* __restrict__ Bsw,
    float* __restrict__ invv_a,
    float* __restrict__ alpha_a,
    float* __restrict__ beta_a)
{
    const int k = blockIdx.x * 4 + (threadIdx.x >> 6);  // class index
    const int l = threadIdx.x & 63;                     // lane: elems 8l..8l+7

    const float* mrow = means + (size_t)k * DIM + l * 8;
    f32x4 v0 = *(const f32x4*)(mrow);
    f32x4 v1 = *(const f32x4*)(mrow + 4);

    u16x8 pk;
    pk[0] = f2bf(v0[0]); pk[1] = f2bf(v0[1]); pk[2] = f2bf(v0[2]); pk[3] = f2bf(v0[3]);
    pk[4] = f2bf(v1[0]); pk[5] = f2bf(v1[1]); pk[6] = f2bf(v1[2]); pk[7] = f2bf(v1[3]);

    const int c16 = k >> 4, r = k & 15, ch = l >> 2, hh = l & 3;
    *(u16x8*)(Bsw + ((((c16 * 16) + ch) * 64) + (hh * 16 + r)) * 8) = pk;

    float sq = v0[0]*v0[0] + v0[1]*v0[1] + v0[2]*v0[2] + v0[3]*v0[3]
             + v1[0]*v1[0] + v1[1]*v1[1] + v1[2]*v1[2] + v1[3]*v1[3];
    #pragma unroll
    for (int m = 1; m <= 32; m <<= 1) sq += __shfl_xor(sq, m);

    if (l == 0) {
        const float lv = log_vars[k];
        const float iv = __expf(-lv);
        invv_a[k]  = iv;
        alpha_a[k] = -0.5f * iv;
        beta_a[k]  = -0.5f * (sq * iv + (float)DIM * lv) + log_weights[k];
    }
}

// ---------------------------------------------------------------------------
// Main fused kernel: 32 rows/block, full K=512 in-block -> fused softmax.
// x-tile staged to LDS once (bf16 in A-fragment order -> conflict-free
// ds_read_b128), one barrier, then a barrier-free K-loop with a 2-stage
// register double-buffer. B-prefetch loads are interleaved 1:1 with MFMAs
// (AITER pattern). __launch_bounds__(256,2) gives the allocator a 256-VGPR
// budget so BOTH pipeline stages stay in registers (at (256,3)=170 the
// allocator spilled and serialized the pipeline: R3 scratch traffic).
// ---------------------------------------------------------------------------
__global__ __launch_bounds__(256, 2) void gmm_main(
    const float* __restrict__ x,
    const uint16_t* __restrict__ Bsw,
    const float* __restrict__ invv_a,
    const float* __restrict__ alpha_a,
    const float* __restrict__ beta_a,
    float* __restrict__ out)
{
    __shared__ uint16_t As[16384];   // 32 KB
    __shared__ float xsq_lds[32];
    __shared__ float pmax[4][32];
    __shared__ float psum[4][32];

    const int t    = threadIdx.x;
    const int w    = t >> 6;        // wave -> col group
    const int lane = t & 63;
    const int r16  = lane & 15;
    const int h    = lane >> 4;
    const int row0 = blockIdx.x * 32;

    // ---- stage x tile -> LDS (fragment order) + xsq ----
    {
        const int srow = t >> 3, sp = t & 7;         // 8 threads per row
        const int rt_s = srow >> 4, r16_s = srow & 15;
        const float* xr = x + (size_t)(row0 + srow) * DIM;
        float xsq_p = 0.f;
        #pragma unroll
        for (int i = 0; i < 8; ++i) {
            const int o = sp + 8 * i;                // k-octet 0..63
            f32x8 v = *(const f32x8*)(xr + 8 * o);
            u16x8 pk;
            #pragma unroll
            for (int j = 0; j < 8; ++j) { xsq_p += v[j] * v[j]; pk[j] = f2bf(v[j]); }
            const int c = o >> 2, hh = o & 3;
            *(u16x8*)&As[(((c * 2 + rt_s) * 64) + hh * 16 + r16_s) * 8] = pk;
        }
        xsq_p += __shfl_xor(xsq_p, 1);
        xsq_p += __shfl_xor(xsq_p, 2);
        xsq_p += __shfl_xor(xsq_p, 4);
        if (sp == 0) xsq_lds[srow] = xsq_p;
    }
    __syncthreads();

    f32x4 acc[2][8];
    #pragma unroll
    for (int rt = 0; rt < 2; ++rt)
        #pragma unroll
        for (int ct = 0; ct < 8; ++ct)
            acc[rt][ct] = (f32x4){0.f, 0.f, 0.f, 0.f};

    const uint16_t* bb = Bsw + (size_t)w * 65536 + (size_t)lane * 8;
    const uint16_t* ab = As + (size_t)lane * 8;     // LDS, frag base

    // ---- software-pipelined K-loop (16 chunks, 2 per unrolled iter) ----
    bf16x8 Aa0, Aa1, Ab0, Ab1, Ba[8], Bb[8];
    Aa0 = *(const bf16x8*)(ab);
    Aa1 = *(const bf16x8*)(ab + 512);
    #pragma unroll
    for (int ct = 0; ct < 8; ++ct) Ba[ct] = *(const bf16x8*)(bb + ct * 8192);

    #pragma unroll
    for (int c2 = 0; c2 < 8; ++c2) {
        const int k1 = 2 * c2 + 1, k2 = 2 * c2 + 2;

        // A prefetch for k1 (LDS), then B-prefetch interleaved 1:1 with MFMAs
        Ab0 = *(const bf16x8*)(ab + k1 * 1024);
        Ab1 = *(const bf16x8*)(ab + k1 * 1024 + 512);
        #pragma unroll
        for (int ct = 0; ct < 8; ++ct) {
            Bb[ct] = *(const bf16x8*)(bb + ct * 8192 + k1 * 512);
            acc[0][ct] = MFMA(Aa0, Ba[ct], acc[0][ct]);
            acc[1][ct] = MFMA(Aa1, Ba[ct], acc[1][ct]);
        }

        if (c2 < 7) {
            Aa0 = *(const bf16x8*)(ab + k2 * 1024);
            Aa1 = *(const bf16x8*)(ab + k2 * 1024 + 512);
        }
        #pragma unroll
        for (int ct = 0; ct < 8; ++ct) {
            if (c2 < 7) Ba[ct] = *(const bf16x8*)(bb + ct * 8192 + k2 * 512);
            acc[0][ct] = MFMA(Ab0, Bb[ct], acc[0][ct]);
            acc[1][ct] = MFMA(Ab1, Bb[ct], acc[1][ct]);
        }
    }

    // ---- per-column affine params (L2-hot) ----
    float invv[8], alf[8], bet[8];
    #pragma unroll
    for (int ct = 0; ct < 8; ++ct) {
        const int col = 128 * w + 16 * ct + r16;
        invv[ct] = invv_a[col];
        alf[ct]  = alpha_a[col];
        bet[ct]  = beta_a[col];
    }
    float xsq[2][4];
    #pragma unroll
    for (int rt = 0; rt < 2; ++rt)
        #pragma unroll
        for (int reg = 0; reg < 4; ++reg)
            xsq[rt][reg] = xsq_lds[16 * rt + 4 * h + reg];

    // ---- logits + per-row max (C layout: col=lane&15, row=4*(lane>>4)+reg) ----
    float mr[2][4];
    #pragma unroll
    for (int rt = 0; rt < 2; ++rt) {
        #pragma unroll
        for (int reg = 0; reg < 4; ++reg) {
            float m = -1e30f;
            #pragma unroll
            for (int ct = 0; ct < 8; ++ct) {
                const float v = acc[rt][ct][reg] * invv[ct] + (alf[ct] * xsq[rt][reg] + bet[ct]);
                acc[rt][ct][reg] = v;
                m = fmaxf(m, v);
            }
            m = fmaxf(m, __shfl_xor(m, 1));
            m = fmaxf(m, __shfl_xor(m, 2));
            m = fmaxf(m, __shfl_xor(m, 4));
            m = fmaxf(m, __shfl_xor(m, 8));
            mr[rt][reg] = m;
        }
    }
    if (r16 == 0) {
        #pragma unroll
        for (int rt = 0; rt < 2; ++rt)
            #pragma unroll
            for (int reg = 0; reg < 4; ++reg)
                pmax[w][16 * rt + 4 * h + reg] = mr[rt][reg];
    }
    __syncthreads();

    // ---- exp + per-row sum ----
    float sr[2][4];
    #pragma unroll
    for (int rt = 0; rt < 2; ++rt) {
        #pragma unroll
        for (int reg = 0; reg < 4; ++reg) {
            const int rl = 16 * rt + 4 * h + reg;
            const float m = fmaxf(fmaxf(pmax[0][rl], pmax[1][rl]),
                                  fmaxf(pmax[2][rl], pmax[3][rl]));
            float s = 0.f;
            #pragma unroll
            for (int ct = 0; ct < 8; ++ct) {
                const float e = __expf(acc[rt][ct][reg] - m);
                acc[rt][ct][reg] = e;
                s += e;
            }
            s += __shfl_xor(s, 1);
            s += __shfl_xor(s, 2);
            s += __shfl_xor(s, 4);
            s += __shfl_xor(s, 8);
            sr[rt][reg] = s;
        }
    }
    if (r16 == 0) {
        #pragma unroll
        for (int rt = 0; rt < 2; ++rt)
            #pragma unroll
            for (int reg = 0; reg < 4; ++reg)
                psum[w][16 * rt + 4 * h + reg] = sr[rt][reg];
    }
    __syncthreads();

    // ---- normalize + store ----
    #pragma unroll
    for (int rt = 0; rt < 2; ++rt) {
        #pragma unroll
        for (int reg = 0; reg < 4; ++reg) {
            const int rl = 16 * rt + 4 * h + reg;
            const float tot = (psum[0][rl] + psum[1][rl]) + (psum[2][rl] + psum[3][rl]);
            const float rinv = 1.0f / tot;
            float* orow = out + (size_t)(row0 + rl) * KCLS + 128 * w + r16;
            #pragma unroll
            for (int ct = 0; ct < 8; ++ct)
                orow[16 * ct] = acc[rt][ct][reg] * rinv;
        }
    }
}

extern "C" void kernel_launch(void* const* d_in, const int* in_sizes, int n_in,
                              void* d_out, int out_size, void* d_ws, size_t ws_size,
                              hipStream_t stream) {
    (void)in_sizes; (void)n_in; (void)out_size; (void)ws_size;
    const float* x           = (const float*)d_in[0];
    const float* means       = (const float*)d_in[1];
    const float* log_vars    = (const float*)d_in[2];
    const float* log_weights = (const float*)d_in[3];
    float* out = (float*)d_out;

    // ws: [0, 512KB) swizzled bf16 means; then inv_var/alpha/beta (512 f32 each)
    uint16_t* Bsw = (uint16_t*)d_ws;
    float* invv_a  = (float*)((char*)d_ws + (512u << 10));
    float* alpha_a = invv_a + KCLS;
    float* beta_a  = alpha_a + KCLS;

    gmm_prep<<<KCLS / 4, 256, 0, stream>>>(means, log_vars, log_weights,
                                           Bsw, invv_a, alpha_a, beta_a);
    gmm_main<<<BATCH / 32, 256, 0, stream>>>(x, Bsw, invv_a, alpha_a, beta_a, out);
}